// Round 1
// baseline (52.068 us; speedup 1.0000x reference)
//
#include <hip/hip_runtime.h>
#include <math.h>

#define RES     32
#define GCELLS  (RES * RES * RES)       // 32768
#define NPTS    32768
#define BATCH   64
#define NPLANES 3
#define EPS_PD  1e-6f
#define WREG_F  25.0f

// ---------------------------------------------------------------------------
// Kernel 1: per-point symmetry loss, grid-stride over B*N points.
// Each thread loads its point once and processes all 3 planes in registers.
// Per-block partial sums -> d_ws (deterministic two-stage reduction).
// ---------------------------------------------------------------------------
__global__ __launch_bounds__(256) void sym_kernel(
    const float* __restrict__ pc,      // (B, N, 3)
    const float* __restrict__ aux,     // (B, G, 3)
    const float* __restrict__ vox,     // (B, G)
    const float* __restrict__ planes,  // (3, B, 4)
    float* __restrict__ part)          // (gridDim.x)
{
    const int total  = BATCH * NPTS;             // 2,097,152
    const int stride = gridDim.x * blockDim.x;

    float acc = 0.0f;

    for (int i = blockIdx.x * blockDim.x + threadIdx.x; i < total; i += stride) {
        const int b = i >> 15;                   // i / NPTS

        const float px = pc[i * 3 + 0];
        const float py = pc[i * 3 + 1];
        const float pz = pc[i * 3 + 2];

        #pragma unroll
        for (int pl = 0; pl < NPLANES; ++pl) {
            const float* P = planes + ((pl * BATCH + b) << 2);
            const float nx = P[0], ny = P[1], nz = P[2], d = P[3];

            const float ln2 = nx * nx + ny * ny + nz * nz;
            const float t   = (px * nx + py * ny + pz * nz + d) / ln2;

            const float qx = px - 2.0f * t * nx;
            const float qy = py - 2.0f * t * ny;
            const float qz = pz - 2.0f * t * nz;

            // idx = trunc-toward-zero of (q + 0.5) * 32, clipped to [0, 31]
            int ix = (int)((qx + 0.5f) * (float)RES);
            int iy = (int)((qy + 0.5f) * (float)RES);
            int iz = (int)((qz + 0.5f) * (float)RES);
            ix = min(RES - 1, max(0, ix));
            iy = min(RES - 1, max(0, iy));
            iz = min(RES - 1, max(0, iz));

            const int g  = ix * (RES * RES) + iy * RES + iz;
            const int gi = b * GCELLS + g;

            const float v  = vox[gi];
            const float tx = aux[gi * 3 + 0];
            const float ty = aux[gi * 3 + 1];
            const float tz = aux[gi * 3 + 2];

            const float dx = qx - tx + EPS_PD;
            const float dy = qy - ty + EPS_PD;
            const float dz = qz - tz + EPS_PD;

            const float dist = sqrtf(dx * dx + dy * dy + dz * dz);
            acc += dist * (1.0f - v);
        }
    }

    // wave (64-lane) reduction
    #pragma unroll
    for (int off = 32; off > 0; off >>= 1)
        acc += __shfl_down(acc, off);

    __shared__ float ws[4];
    const int lane = threadIdx.x & 63;
    const int wid  = threadIdx.x >> 6;
    if (lane == 0) ws[wid] = acc;
    __syncthreads();

    if (threadIdx.x == 0)
        part[blockIdx.x] = ws[0] + ws[1] + ws[2] + ws[3];
}

// ---------------------------------------------------------------------------
// Kernel 2: single block. Sums block partials, adds the plane-normal
// regularizer, writes the final scalar. Fully deterministic.
// ---------------------------------------------------------------------------
__global__ __launch_bounds__(256) void finalize_kernel(
    const float* __restrict__ part, int n_part,
    const float* __restrict__ planes,  // (3, B, 4)
    float* __restrict__ out)
{
    __shared__ float sdata[256];

    float s = 0.0f;
    for (int i = threadIdx.x; i < n_part; i += 256)
        s += part[i];

    float r = 0.0f;
    if (threadIdx.x < BATCH) {
        const int b = threadIdx.x;
        float nv[3][3];
        #pragma unroll
        for (int p = 0; p < NPLANES; ++p) {
            const float nx = planes[((p * BATCH + b) << 2) + 0];
            const float ny = planes[((p * BATCH + b) << 2) + 1];
            const float nz = planes[((p * BATCH + b) << 2) + 2];
            float nrm = sqrtf(nx * nx + ny * ny + nz * nz);
            nrm = fmaxf(nrm, 1e-12f);
            nv[p][0] = nx / nrm;
            nv[p][1] = ny / nrm;
            nv[p][2] = nz / nrm;
        }
        #pragma unroll
        for (int i2 = 0; i2 < 3; ++i2) {
            #pragma unroll
            for (int j = 0; j < 3; ++j) {
                const float m = nv[i2][j] * nv[j][i2] - (i2 == j ? 1.0f : 0.0f);
                r += m * m;
            }
        }
    }

    // combined scalar contribution of this thread
    float val = s * (1.0f / (float)BATCH) + r * (WREG_F / (float)BATCH);

    sdata[threadIdx.x] = val;
    __syncthreads();
    #pragma unroll
    for (int off = 128; off > 0; off >>= 1) {
        if (threadIdx.x < off) sdata[threadIdx.x] += sdata[threadIdx.x + off];
        __syncthreads();
    }

    if (threadIdx.x == 0) out[0] = sdata[0];
}

// ---------------------------------------------------------------------------
extern "C" void kernel_launch(void* const* d_in, const int* in_sizes, int n_in,
                              void* d_out, int out_size, void* d_ws, size_t ws_size,
                              hipStream_t stream)
{
    const float* pc     = (const float*)d_in[0];  // point_cloud (64, 32768, 3)
    const float* aux    = (const float*)d_in[1];  // auxiliary_data (64, 32768, 3)
    const float* vox    = (const float*)d_in[2];  // voxel_data (64, 32768, 1)
    const float* planes = (const float*)d_in[3];  // planes (3, 64, 4)
    float* out  = (float*)d_out;
    float* part = (float*)d_ws;                   // 2048 floats of scratch

    const int blocks  = 2048;
    const int threads = 256;

    sym_kernel<<<blocks, threads, 0, stream>>>(pc, aux, vox, planes, part);
    finalize_kernel<<<1, 256, 0, stream>>>(part, blocks, planes, out);
}